// Round 14
// baseline (2838.175 us; speedup 1.0000x reference)
//
#include <hip/hip_runtime.h>
#include <math.h>

#define BS 32
#define M 64
#define NMAT 2048      // BS*M
#define DIN 100
#define DOUT 64
#define DD 4096        // DOUT*DOUT
#define EPSV 1e-6f
#define NSWEEP_1S 6
#define DS_SPLIT 32    // elements [0,DS_SPLIT) via ds_bpermute, rest via VALU
                       // (R14: with 256-VGPR cap the AGPR staging disappears,
                       //  VALU path ~4.5 inst/elem -> balance moves to x=32)
#define LSTR 68        // LDS row stride for matmul tiles: 16B-aligned, <=2-way bank alias

typedef unsigned int uint2v __attribute__((ext_vector_type(2)));

__device__ __forceinline__ float bperm(int addr, float v) {
    return __int_as_float(__builtin_amdgcn_ds_bpermute(addr, __float_as_int(v)));
}

// DPP lane permute (VALU pipe): 0xB1=lane^1, 0x4E=lane^2, 0x1B=lane^3,
// 0x141=lane^7 (row_half_mirror), 0x140=lane^15 (row_mirror).
template <int CTRL>
__device__ __forceinline__ float dppf(float x) {
    return __int_as_float(__builtin_amdgcn_mov_dpp(__float_as_int(x), CTRL, 0xF, 0xF, true));
}

// Full lane^32 of TWO independent values in 2 instructions (no cndmask):
// swap(a,b): a'=[a_lo,b_lo], b'=[a_hi,b_hi]  (validated R8/R9)
__device__ __forceinline__ void swap32_pair(float& x, float& y) {
#if __has_builtin(__builtin_amdgcn_permlane32_swap)
    uint2v r1 = __builtin_amdgcn_permlane32_swap(__float_as_uint(x), __float_as_uint(y), false, false);
    uint2v r2 = __builtin_amdgcn_permlane32_swap(r1[1], r1[0], false, false);
    x = __uint_as_float(r2[0]);
    y = __uint_as_float(r2[1]);
#else
    int a = ((threadIdx.x & 63) ^ 32) << 2;
    x = bperm(a, x); y = bperm(a, y);
#endif
}
__device__ __forceinline__ void swap16_pair(float& x, float& y) {
#if __has_builtin(__builtin_amdgcn_permlane16_swap)
    uint2v r1 = __builtin_amdgcn_permlane16_swap(__float_as_uint(x), __float_as_uint(y), false, false);
    uint2v r2 = __builtin_amdgcn_permlane16_swap(r1[1], r1[0], false, false);
    x = __uint_as_float(r2[0]);
    y = __uint_as_float(r2[1]);
#else
    int a = ((threadIdx.x & 63) ^ 16) << 2;
    x = bperm(a, x); y = bperm(a, y);
#endif
}

// ---------------- transform: S = W^T X W for each of q,k,v ----------------
__global__ __launch_bounds__(256) void transform_kernel(
    const float* __restrict__ x,
    const float* __restrict__ Wq, const float* __restrict__ Wk, const float* __restrict__ Wv,
    float* __restrict__ Qo, float* __restrict__ Ko, float* __restrict__ Vo)
{
    __shared__ float Xs[DIN][DIN + 1];      // 100x101
    __shared__ float Ws[DIN][DOUT + 1];     // 100x65
    __shared__ float Ts[DIN][DOUT + 1];     // 100x65
    const int n = blockIdx.x;
    const int t = threadIdx.x;
    const float* Xp = x + (size_t)n * DIN * DIN;
    for (int idx = t; idx < DIN * DIN; idx += 256)
        Xs[idx / DIN][idx % DIN] = Xp[idx];

    const float* Wlist[3] = {Wq, Wk, Wv};
    float* Olist[3] = {Qo, Ko, Vo};
    const int tj = t & 63;   // 0..63
    const int tp = t >> 6;   // 0..3

    for (int w = 0; w < 3; ++w) {
        __syncthreads();     // Xs ready (w=0); Ws/Ts free (w>0)
        const float* W = Wlist[w];
        for (int idx = t; idx < DIN * DOUT; idx += 256)
            Ws[idx / DOUT][idx % DOUT] = W[idx];
        __syncthreads();
        // T = X * W : thread computes T[p][tj] for p = tp + 4*pi
        float acc[25];
        #pragma unroll
        for (int i = 0; i < 25; ++i) acc[i] = 0.f;
        for (int qq = 0; qq < DIN; ++qq) {
            float wv = Ws[qq][tj];
            #pragma unroll
            for (int pi = 0; pi < 25; ++pi)
                acc[pi] += Xs[tp + 4 * pi][qq] * wv;
        }
        #pragma unroll
        for (int pi = 0; pi < 25; ++pi)
            Ts[tp + 4 * pi][tj] = acc[pi];
        __syncthreads();
        // S = W^T * T : thread computes S[i][tj] for i = tp + 4*ii
        float sacc[16];
        #pragma unroll
        for (int i = 0; i < 16; ++i) sacc[i] = 0.f;
        for (int p = 0; p < DIN; ++p) {
            float tv = Ts[p][tj];
            #pragma unroll
            for (int ii = 0; ii < 16; ++ii)
                sacc[ii] += Ws[p][tp + 4 * ii] * tv;
        }
        float* Op = Olist[w] + (size_t)n * DD;
        #pragma unroll
        for (int ii = 0; ii < 16; ++ii)
            Op[(tp + 4 * ii) * DOUT + tj] = sacc[ii];
    }
}

// ---------------- one-sided Jacobi (SVD) — one wave per matrix ------------
// Two-pipe exchange: elements [0,32) DS (bpermute), [32,64) VALU (DPP +
// permlane pair-swaps). __launch_bounds__(256,2): 256-VGPR cap lets
// g[64]+gp[64] live entirely in arch VGPRs (R13's (256,3) cap=170 forced
// 84 arch + 85 AGPR with accvgpr traffic on every gp use). 6 sweeps.
// Arithmetic identical to R13 -> bit-identical output (0.01953125).
__global__ __launch_bounds__(256, 2) void jacobi1s_kernel(
    float* __restrict__ Q, float* __restrict__ K, float* __restrict__ V,
    float* __restrict__ wbuf, float* __restrict__ qn, float* __restrict__ kn)
{
    const int lane = threadIdx.x & 63;
    const int wid  = threadIdx.x >> 6;
    const int mat  = blockIdx.x * 4 + wid;
    float* base;
    float* nrm = nullptr;
    if (mat < NMAT)          { base = Q + (size_t)mat * DD;            nrm = qn + mat; }
    else if (mat < 2 * NMAT) { base = K + (size_t)(mat - NMAT) * DD;   nrm = kn + (mat - NMAT); }
    else                     { base = V + (size_t)(mat - 2 * NMAT) * DD; }

    // Lane `lane` owns column `lane`. A is symmetric -> column == row.
    float g[64];
    {
        const float4* rp = (const float4*)(base + (size_t)lane * DOUT);
        #pragma unroll
        for (int i = 0; i < 16; ++i) {
            float4 v = rp[i];
            g[4 * i + 0] = v.x; g[4 * i + 1] = v.y;
            g[4 * i + 2] = v.z; g[4 * i + 3] = v.w;
        }
    }

    for (int sw = 0; sw < NSWEEP_1S; ++sw) {
        // exact norm at sweep start (kills incremental drift)
        float nself;
        {
            float n0 = 0.f, n1 = 0.f, n2 = 0.f, n3 = 0.f;
            #pragma unroll
            for (int i = 0; i < 64; i += 4) {
                n0 = fmaf(g[i + 0], g[i + 0], n0);
                n1 = fmaf(g[i + 1], g[i + 1], n1);
                n2 = fmaf(g[i + 2], g[i + 2], n2);
                n3 = fmaf(g[i + 3], g[i + 3], n3);
            }
            nself = (n0 + n1) + (n2 + n3);
        }
        #pragma unroll 1
        for (int rr = 0; rr < 63; ++rr) {
            const int Kx = rr + 1;
            const int partner = lane ^ Kx;
            const int paddr = partner << 2;
            const float dpart = bperm(paddr, nself);

            float gp[64];
            // ---- DS portion: elements [0,DS_SPLIT) via bpermute ----
            #pragma unroll
            for (int i = 0; i < DS_SPLIT; ++i) gp[i] = bperm(paddr, g[i]);
            // ---- VALU portion: elements [DS_SPLIT,64) via DPP/permlane ----
            #pragma unroll
            for (int i = DS_SPLIT; i < 64; ++i) gp[i] = g[i];
            if (Kx & 32) {
                #pragma unroll
                for (int i = DS_SPLIT; i < 64; i += 2) swap32_pair(gp[i], gp[i + 1]);
            }
            if (Kx & 16) {
                #pragma unroll
                for (int i = DS_SPLIT; i < 64; i += 2) swap16_pair(gp[i], gp[i + 1]);
            }
            {
                const int low4 = Kx & 15;
                const bool m_f = (low4 & 8) != 0;
                const int n4 = m_f ? (low4 ^ 15) : low4;
                const bool h_f = (n4 & 4) != 0;
                const int q = h_f ? (n4 ^ 7) : n4;   // 0..3
                if (m_f) {
                    #pragma unroll
                    for (int i = DS_SPLIT; i < 64; ++i) gp[i] = dppf<0x140>(gp[i]);
                }
                if (h_f) {
                    #pragma unroll
                    for (int i = DS_SPLIT; i < 64; ++i) gp[i] = dppf<0x141>(gp[i]);
                }
                if (q == 1) {
                    #pragma unroll
                    for (int i = DS_SPLIT; i < 64; ++i) gp[i] = dppf<0xB1>(gp[i]);
                } else if (q == 2) {
                    #pragma unroll
                    for (int i = DS_SPLIT; i < 64; ++i) gp[i] = dppf<0x4E>(gp[i]);
                } else if (q == 3) {
                    #pragma unroll
                    for (int i = DS_SPLIT; i < 64; ++i) gp[i] = dppf<0x1B>(gp[i]);
                }
            }

            // dot via 4 split chains
            float d0 = 0.f, d1 = 0.f, d2 = 0.f, d3 = 0.f;
            #pragma unroll
            for (int i = 0; i < 64; i += 4) {
                d0 = fmaf(g[i + 0], gp[i + 0], d0);
                d1 = fmaf(g[i + 1], gp[i + 1], d1);
                d2 = fmaf(g[i + 2], gp[i + 2], d2);
                d3 = fmaf(g[i + 3], gp[i + 3], d3);
            }
            const float dot = (d0 + d1) + (d2 + d3);

            // rotation params for ordered pair (p,q) = (min,max)
            const bool isp = lane < partner;
            const float dpp = isp ? nself : dpart;
            const float dqq = isp ? dpart : nself;
            float c = 1.f, s = 0.f, tt = 0.f;
            if (dot * dot > 1e-16f * dpp * dqq) {
                float theta = (dqq - dpp) / (2.f * dot);
                tt = 1.f / (fabsf(theta) + sqrtf(1.f + theta * theta));
                if (theta < 0.f) tt = -tt;
                c = rsqrtf(1.f + tt * tt);
                s = tt * c;
            }
            const float sgn = isp ? -s : s;
            #pragma unroll
            for (int i = 0; i < 64; ++i)
                g[i] = fmaf(c, g[i], sgn * gp[i]);
            nself = fmaf(isp ? -tt : tt, dot, nself);
        }
    }

    // epilogue: sigma, f = log(sigma+eps), w = f/sigma^2
    float d;
    {
        float n0 = 0.f, n1 = 0.f, n2 = 0.f, n3 = 0.f;
        #pragma unroll
        for (int i = 0; i < 64; i += 4) {
            n0 = fmaf(g[i + 0], g[i + 0], n0);
            n1 = fmaf(g[i + 1], g[i + 1], n1);
            n2 = fmaf(g[i + 2], g[i + 2], n2);
            n3 = fmaf(g[i + 3], g[i + 3], n3);
        }
        d = (n0 + n1) + (n2 + n3);
    }
    float sigma = sqrtf(d);
    float f = logf(sigma + EPSV);
    float w = f / d;

    // write G back (lane's column scattered across rows -> coalesced stores)
    #pragma unroll
    for (int i = 0; i < 64; ++i) base[i * DOUT + lane] = g[i];
    wbuf[(size_t)mat * 64 + lane] = w;

    if (nrm != nullptr) {
        float nf = f * f;
        #pragma unroll
        for (int off = 32; off >= 1; off >>= 1) nf += __shfl_xor(nf, off, 64);
        if (lane == 0) *nrm = nf;
    }
}

// ---------------- reconstruction: logA = G diag(w) G^T, in place ----------
// float4 LDS reads in k-chunks of 4 (stride LSTR=68: 16B-aligned rows,
// <=2-way bank alias). Same fma order as scalar version -> bit-identical.
__global__ __launch_bounds__(256) void recon_log_kernel(
    float* __restrict__ Q, float* __restrict__ K, float* __restrict__ V,
    const float* __restrict__ wbuf)
{
    __shared__ float Gs[64][LSTR];
    __shared__ float Bs[64][LSTR];
    __shared__ float ws[64];
    const int t = threadIdx.x;
    const int mat = blockIdx.x;
    float* base;
    if (mat < NMAT)          base = Q + (size_t)mat * DD;
    else if (mat < 2 * NMAT) base = K + (size_t)(mat - NMAT) * DD;
    else                     base = V + (size_t)(mat - 2 * NMAT) * DD;

    for (int idx = t; idx < DD; idx += 256)
        Gs[idx >> 6][idx & 63] = base[idx];
    if (t < 64) ws[t] = wbuf[(size_t)mat * 64 + t];
    __syncthreads();
    for (int idx = t; idx < DD; idx += 256) {
        int r = idx >> 6, c = idx & 63;
        Bs[r][c] = Gs[r][c] * ws[c];
    }
    __syncthreads();
    // out[i][j] = sum_k Bs[i][k] * Gs[j][k] ; 4x4 register tile per thread
    const int ti = t >> 4, tj = t & 15;
    float acc[4][4];
    #pragma unroll
    for (int i = 0; i < 4; ++i)
        #pragma unroll
        for (int j = 0; j < 4; ++j) acc[i][j] = 0.f;
    for (int k4 = 0; k4 < 64; k4 += 4) {
        float4 a[4], b[4];
        #pragma unroll
        for (int d = 0; d < 4; ++d) a[d] = *(const float4*)&Bs[4 * ti + d][k4];
        #pragma unroll
        for (int d = 0; d < 4; ++d) b[d] = *(const float4*)&Gs[4 * tj + d][k4];
        #pragma unroll
        for (int kk = 0; kk < 4; ++kk) {
            #pragma unroll
            for (int i = 0; i < 4; ++i) {
                float av = ((const float*)&a[i])[kk];
                #pragma unroll
                for (int j = 0; j < 4; ++j)
                    acc[i][j] += av * ((const float*)&b[j])[kk];
            }
        }
    }
    #pragma unroll
    for (int i = 0; i < 4; ++i) {
        float4 v;
        v.x = acc[i][0]; v.y = acc[i][1]; v.z = acc[i][2]; v.w = acc[i][3];
        *(float4*)(base + (4 * ti + i) * DOUT + 4 * tj) = v;
    }
}

// ---------------- scores + softmax (per batch) ----------------------------
__global__ __launch_bounds__(256) void scores_kernel(
    const float* __restrict__ logK, const float* __restrict__ logQ,
    const float* __restrict__ kn, const float* __restrict__ qn,
    float* __restrict__ prob)
{
    __shared__ float kf_t[64][65];
    __shared__ float qf_t[64][65];
    __shared__ float sc[64][65];
    __shared__ float mx[64], sm[64];
    const int b = blockIdx.x;
    const int t = threadIdx.x;
    const int ti = t >> 4, tjj = t & 15;
    float acc[4][4];
    #pragma unroll
    for (int di = 0; di < 4; ++di)
        #pragma unroll
        for (int dj = 0; dj < 4; ++dj) acc[di][dj] = 0.f;

    const float* Kb = logK + (size_t)b * M * DD;
    const float* Qb = logQ + (size_t)b * M * DD;
    for (int cf = 0; cf < DD; cf += 64) {
        __syncthreads();
        for (int idx = t; idx < 64 * 64; idx += 256) {
            int r = idx >> 6, c = idx & 63;
            kf_t[r][c] = Kb[(size_t)r * DD + cf + c];
            qf_t[r][c] = Qb[(size_t)r * DD + cf + c];
        }
        __syncthreads();
        for (int f = 0; f < 64; ++f) {
            float kv[4], qv[4];
            #pragma unroll
            for (int d = 0; d < 4; ++d) { kv[d] = kf_t[4 * ti + d][f]; qv[d] = qf_t[4 * tjj + d][f]; }
            #pragma unroll
            for (int di = 0; di < 4; ++di)
                #pragma unroll
                for (int dj = 0; dj < 4; ++dj)
                    acc[di][dj] += kv[di] * qv[dj];
        }
    }
    __syncthreads();
    #pragma unroll
    for (int di = 0; di < 4; ++di) {
        #pragma unroll
        for (int dj = 0; dj < 4; ++dj) {
            int i = 4 * ti + di, j = 4 * tjj + dj;
            float dist = kn[b * 64 + i] + qn[b * 64 + j] - 2.f * acc[di][dj];
            dist = fmaxf(dist, 0.f) + 64.f * EPSV;
            sc[i][j] = 1.f / (1.f + log1pf(dist));
        }
    }
    __syncthreads();
    if (t < 64) {
        int j = t;
        float m = -1e30f;
        for (int i = 0; i < 64; ++i) m = fmaxf(m, sc[i][j]);
        float ssum = 0.f;
        for (int i = 0; i < 64; ++i) ssum += expf(sc[i][j] - m);
        mx[j] = m; sm[j] = ssum;
    }
    __syncthreads();
    float* Pb = prob + (size_t)b * M * M;
    for (int idx = t; idx < 64 * 64; idx += 256) {
        int j = idx >> 6, i = idx & 63;
        Pb[idx] = expf(sc[i][j] - mx[j]) / sm[j];
    }
}

// ---------------- mixed = prob @ vf  (one block per output row) -----------
__global__ __launch_bounds__(256) void mixed_kernel(
    const float* __restrict__ prob, const float* __restrict__ logV,
    float* __restrict__ mixed)
{
    __shared__ float pr[64];
    const int n = blockIdx.x;        // b*64 + j
    const int b = n >> 6, j = n & 63;
    const int t = threadIdx.x;
    if (t < 64) pr[t] = prob[((size_t)b * 64 + j) * 64 + t];
    __syncthreads();
    const float4* Vb = (const float4*)(logV + (size_t)b * M * DD);
    float4 acc[4];
    #pragma unroll
    for (int u = 0; u < 4; ++u) acc[u] = make_float4(0.f, 0.f, 0.f, 0.f);
    for (int i = 0; i < 64; ++i) {
        float p = pr[i];
        const float4* row = Vb + (size_t)i * (DD / 4);
        #pragma unroll
        for (int u = 0; u < 4; ++u) {
            float4 v = row[t + 256 * u];
            acc[u].x += p * v.x; acc[u].y += p * v.y;
            acc[u].z += p * v.z; acc[u].w += p * v.w;
        }
    }
    float4* Mp = (float4*)(mixed + (size_t)n * DD);
    #pragma unroll
    for (int u = 0; u < 4; ++u) Mp[t + 256 * u] = acc[u];
}

// ---------------- exp via scaling-and-squaring Taylor (deg 8) -------------
// mm64: A-side float4 over k (chunks of 4), B-side float4 over j.
__device__ __forceinline__ void mm64(const float (*A)[LSTR], const float (*B)[LSTR],
                                     float (*C)[LSTR], int t)
{
    const int ti = t >> 4, tj = t & 15;
    float acc[4][4];
    #pragma unroll
    for (int i = 0; i < 4; ++i)
        #pragma unroll
        for (int j = 0; j < 4; ++j) acc[i][j] = 0.f;
    for (int k4 = 0; k4 < 64; k4 += 4) {
        float4 a[4];
        #pragma unroll
        for (int d = 0; d < 4; ++d) a[d] = *(const float4*)&A[4 * ti + d][k4];
        #pragma unroll
        for (int kk = 0; kk < 4; ++kk) {
            float4 bv = *(const float4*)&B[k4 + kk][4 * tj];
            #pragma unroll
            for (int i = 0; i < 4; ++i) {
                float av = ((const float*)&a[i])[kk];
                acc[i][0] += av * bv.x;
                acc[i][1] += av * bv.y;
                acc[i][2] += av * bv.z;
                acc[i][3] += av * bv.w;
            }
        }
    }
    #pragma unroll
    for (int i = 0; i < 4; ++i)
        #pragma unroll
        for (int j = 0; j < 4; ++j)
            C[4 * ti + i][4 * tj + j] = acc[i][j];
}

__global__ __launch_bounds__(256) void exp_ss_kernel(
    const float* __restrict__ in, float* __restrict__ out)
{
    __shared__ float Bs[64][LSTR];
    __shared__ float Ps[64][LSTR];
    __shared__ float Ts[64][LSTR];
    __shared__ float red[64];
    __shared__ int s_sh;
    __shared__ float scl_sh;
    const int t = threadIdx.x;
    const float* Ap = in + (size_t)blockIdx.x * DD;
    float* Gp = out + (size_t)blockIdx.x * DD;

    for (int idx = t; idx < DD; idx += 256) {
        Bs[idx >> 6][idx & 63] = Ap[idx];
    }
    __syncthreads();
    if (t < 64) {
        float s = 0.f;
        for (int c = 0; c < 64; ++c) s += fabsf(Bs[t][c]);
        red[t] = s;
    }
    __syncthreads();
    if (t == 0) {
        float mx = 0.f;
        for (int k = 0; k < 64; ++k) mx = fmaxf(mx, red[k]);
        int s = 0;
        while (mx > 0.7f && s < 30) { mx *= 0.5f; ++s; }
        s_sh = s;
        scl_sh = ldexpf(1.f, -s);
    }
    __syncthreads();
    const int nsq = s_sh;
    const float scl = scl_sh;
    // scale B in place; init P = I + B/8  (degree-8 Taylor, ||B||1 <= 0.7)
    for (int idx = t; idx < DD; idx += 256) {
        int r = idx >> 6, c = idx & 63;
        float b = Bs[r][c] * scl;
        Bs[r][c] = b;
        Ps[r][c] = b * 0.125f + ((r == c) ? 1.f : 0.f);
    }
    __syncthreads();
    // Horner: P <- I + (B*P)/k for k = 7..1
    #pragma unroll 1
    for (int k = 7; k >= 1; --k) {
        mm64(Bs, Ps, Ts, t);
        __syncthreads();
        float rk = 1.f / (float)k;
        for (int idx = t; idx < DD; idx += 256) {
            int r = idx >> 6, c = idx & 63;
            Ps[r][c] = Ts[r][c] * rk + ((r == c) ? 1.f : 0.f);
        }
        __syncthreads();
    }
    // squarings
    #pragma unroll 1
    for (int j = 0; j < nsq; ++j) {
        mm64(Ps, Ps, Ts, t);
        __syncthreads();
        for (int idx = t; idx < DD; idx += 256)
            Ps[idx >> 6][idx & 63] = Ts[idx >> 6][idx & 63];
        __syncthreads();
    }
    for (int idx = t; idx < DD; idx += 256)
        Gp[idx] = Ps[idx >> 6][idx & 63];
}

extern "C" void kernel_launch(void* const* d_in, const int* in_sizes, int n_in,
                              void* d_out, int out_size, void* d_ws, size_t ws_size,
                              hipStream_t stream) {
    const float* x  = (const float*)d_in[0];
    const float* Wq = (const float*)d_in[1];
    const float* Wk = (const float*)d_in[2];
    const float* Wv = (const float*)d_in[3];
    float* out = (float*)d_out;
    float* ws  = (float*)d_ws;

    // ws layout (floats): Q | K | qn | kn | prob | wbuf ; V/logV in d_out.
    float* Q    = ws;
    float* K    = Q + (size_t)NMAT * DD;
    float* qn   = K + (size_t)NMAT * DD;
    float* kn   = qn + NMAT;
    float* prob = kn + NMAT;
    float* wbuf = prob + (size_t)BS * M * M;
    float* V    = out;        // logV staged in d_out
    float* mixed = Q;         // overwrites logQ after scores

    transform_kernel<<<NMAT, 256, 0, stream>>>(x, Wq, Wk, Wv, Q, K, V);
    jacobi1s_kernel<<<(3 * NMAT) / 4, 256, 0, stream>>>(Q, K, V, wbuf, qn, kn);
    recon_log_kernel<<<3 * NMAT, 256, 0, stream>>>(Q, K, V, wbuf);
    scores_kernel<<<BS, 256, 0, stream>>>(K, Q, kn, qn, prob);
    mixed_kernel<<<NMAT, 256, 0, stream>>>(prob, V, mixed);
    exp_ss_kernel<<<NMAT, 256, 0, stream>>>(mixed, out);
}

// Round 15
// 2298.416 us; speedup vs baseline: 1.2348x; 1.2348x over previous
//
#include <hip/hip_runtime.h>
#include <math.h>

#define BS 32
#define M 64
#define NMAT 2048      // BS*M
#define DIN 100
#define DOUT 64
#define DD 4096        // DOUT*DOUT
#define EPSV 1e-6f
#define NSWEEP_1S 6
#define DS_SPLIT 44    // R13 optimum: [0,44) ds_bpermute, [44,64) VALU
#define LSTR 68        // LDS row stride for matmul tiles: 16B-aligned, <=2-way bank alias
#define WSTR 68        // Ws stride in transform (16B-aligned float4 rows)

typedef unsigned int uint2v __attribute__((ext_vector_type(2)));

__device__ __forceinline__ float bperm(int addr, float v) {
    return __int_as_float(__builtin_amdgcn_ds_bpermute(addr, __float_as_int(v)));
}

// DPP lane permute (VALU pipe): 0xB1=lane^1, 0x4E=lane^2, 0x1B=lane^3,
// 0x141=lane^7 (row_half_mirror), 0x140=lane^15 (row_mirror).
template <int CTRL>
__device__ __forceinline__ float dppf(float x) {
    return __int_as_float(__builtin_amdgcn_mov_dpp(__float_as_int(x), CTRL, 0xF, 0xF, true));
}

// Full lane^32 of TWO independent values in 2 instructions (no cndmask):
// swap(a,b): a'=[a_lo,b_lo], b'=[a_hi,b_hi]  (validated R8/R9)
__device__ __forceinline__ void swap32_pair(float& x, float& y) {
#if __has_builtin(__builtin_amdgcn_permlane32_swap)
    uint2v r1 = __builtin_amdgcn_permlane32_swap(__float_as_uint(x), __float_as_uint(y), false, false);
    uint2v r2 = __builtin_amdgcn_permlane32_swap(r1[1], r1[0], false, false);
    x = __uint_as_float(r2[0]);
    y = __uint_as_float(r2[1]);
#else
    int a = ((threadIdx.x & 63) ^ 32) << 2;
    x = bperm(a, x); y = bperm(a, y);
#endif
}
__device__ __forceinline__ void swap16_pair(float& x, float& y) {
#if __has_builtin(__builtin_amdgcn_permlane16_swap)
    uint2v r1 = __builtin_amdgcn_permlane16_swap(__float_as_uint(x), __float_as_uint(y), false, false);
    uint2v r2 = __builtin_amdgcn_permlane16_swap(r1[1], r1[0], false, false);
    x = __uint_as_float(r2[0]);
    y = __uint_as_float(r2[1]);
#else
    int a = ((threadIdx.x & 63) ^ 16) << 2;
    x = bperm(a, x); y = bperm(a, y);
#endif
}

// ---------------- transform: S = W^T X W for each of q,k,v ----------------
// R15: X read directly from global (broadcast float4 along k, L1-cached) —
// removes the 40KB Xs stage -> LDS 53KB -> 3 blocks/CU (was 1). Ws reads in
// the S loop vectorized (stride 68, i = 16*tp+ii contiguous). Per-output
// k-ascending sum order preserved -> bit-identical to R13.
__global__ __launch_bounds__(256) void transform_kernel(
    const float* __restrict__ x,
    const float* __restrict__ Wq, const float* __restrict__ Wk, const float* __restrict__ Wv,
    float* __restrict__ Qo, float* __restrict__ Ko, float* __restrict__ Vo)
{
    __shared__ float Ws[DIN][WSTR];     // 100x68 = 27.2KB
    __shared__ float Ts[DIN][DOUT + 1]; // 100x65 = 26KB
    const int n = blockIdx.x;
    const int t = threadIdx.x;
    const float* Xp = x + (size_t)n * DIN * DIN;

    const float* Wlist[3] = {Wq, Wk, Wv};
    float* Olist[3] = {Qo, Ko, Vo};
    const int tj = t & 63;   // 0..63
    const int tp = t >> 6;   // 0..3

    for (int w = 0; w < 3; ++w) {
        __syncthreads();     // Ws/Ts free
        const float* W = Wlist[w];
        for (int idx = t; idx < DIN * DOUT; idx += 256)
            Ws[idx / DOUT][idx % DOUT] = W[idx];
        __syncthreads();
        // T = X * W : thread computes T[p][tj] for p = tp + 4*pi.
        // X rows read from global as float4 along k (qq) — broadcast addr.
        float acc[25];
        #pragma unroll
        for (int i = 0; i < 25; ++i) acc[i] = 0.f;
        for (int qq = 0; qq < DIN; qq += 4) {
            float4 xv[25];
            #pragma unroll
            for (int pi = 0; pi < 25; ++pi)
                xv[pi] = *(const float4*)&Xp[(size_t)(tp + 4 * pi) * DIN + qq];
            #pragma unroll
            for (int kk = 0; kk < 4; ++kk) {
                float wv = Ws[qq + kk][tj];
                #pragma unroll
                for (int pi = 0; pi < 25; ++pi)
                    acc[pi] = fmaf(((const float*)&xv[pi])[kk], wv, acc[pi]);
            }
        }
        #pragma unroll
        for (int pi = 0; pi < 25; ++pi)
            Ts[tp + 4 * pi][tj] = acc[pi];
        __syncthreads();
        // S = W^T * T : thread computes S[i][tj] for i = 16*tp + ii
        // (contiguous i-range -> float4 Ws reads; sum over p ascending)
        float sacc[16];
        #pragma unroll
        for (int i = 0; i < 16; ++i) sacc[i] = 0.f;
        for (int p = 0; p < DIN; ++p) {
            float tv = Ts[p][tj];
            #pragma unroll
            for (int v = 0; v < 4; ++v) {
                float4 wv = *(const float4*)&Ws[p][16 * tp + 4 * v];
                sacc[4 * v + 0] = fmaf(wv.x, tv, sacc[4 * v + 0]);
                sacc[4 * v + 1] = fmaf(wv.y, tv, sacc[4 * v + 1]);
                sacc[4 * v + 2] = fmaf(wv.z, tv, sacc[4 * v + 2]);
                sacc[4 * v + 3] = fmaf(wv.w, tv, sacc[4 * v + 3]);
            }
        }
        float* Op = Olist[w] + (size_t)n * DD;
        #pragma unroll
        for (int ii = 0; ii < 16; ++ii)
            Op[(16 * tp + ii) * DOUT + tj] = sacc[ii];
    }
}

// ---------------- one-sided Jacobi (SVD) — one wave per matrix ------------
// R13 optimum (1527us): two-pipe exchange, [0,44) DS bpermute, [44,64) VALU
// (DPP + permlane pair-swaps), __launch_bounds__(256,3), 6 sweeps.
__global__ __launch_bounds__(256, 3) void jacobi1s_kernel(
    float* __restrict__ Q, float* __restrict__ K, float* __restrict__ V,
    float* __restrict__ wbuf, float* __restrict__ qn, float* __restrict__ kn)
{
    const int lane = threadIdx.x & 63;
    const int wid  = threadIdx.x >> 6;
    const int mat  = blockIdx.x * 4 + wid;
    float* base;
    float* nrm = nullptr;
    if (mat < NMAT)          { base = Q + (size_t)mat * DD;            nrm = qn + mat; }
    else if (mat < 2 * NMAT) { base = K + (size_t)(mat - NMAT) * DD;   nrm = kn + (mat - NMAT); }
    else                     { base = V + (size_t)(mat - 2 * NMAT) * DD; }

    // Lane `lane` owns column `lane`. A is symmetric -> column == row.
    float g[64];
    {
        const float4* rp = (const float4*)(base + (size_t)lane * DOUT);
        #pragma unroll
        for (int i = 0; i < 16; ++i) {
            float4 v = rp[i];
            g[4 * i + 0] = v.x; g[4 * i + 1] = v.y;
            g[4 * i + 2] = v.z; g[4 * i + 3] = v.w;
        }
    }

    for (int sw = 0; sw < NSWEEP_1S; ++sw) {
        // exact norm at sweep start (kills incremental drift)
        float nself;
        {
            float n0 = 0.f, n1 = 0.f, n2 = 0.f, n3 = 0.f;
            #pragma unroll
            for (int i = 0; i < 64; i += 4) {
                n0 = fmaf(g[i + 0], g[i + 0], n0);
                n1 = fmaf(g[i + 1], g[i + 1], n1);
                n2 = fmaf(g[i + 2], g[i + 2], n2);
                n3 = fmaf(g[i + 3], g[i + 3], n3);
            }
            nself = (n0 + n1) + (n2 + n3);
        }
        #pragma unroll 1
        for (int rr = 0; rr < 63; ++rr) {
            const int Kx = rr + 1;
            const int partner = lane ^ Kx;
            const int paddr = partner << 2;
            const float dpart = bperm(paddr, nself);

            float gp[64];
            // ---- DS portion: elements [0,DS_SPLIT) via bpermute ----
            #pragma unroll
            for (int i = 0; i < DS_SPLIT; ++i) gp[i] = bperm(paddr, g[i]);
            // ---- VALU portion: elements [DS_SPLIT,64) via DPP/permlane ----
            #pragma unroll
            for (int i = DS_SPLIT; i < 64; ++i) gp[i] = g[i];
            if (Kx & 32) {
                #pragma unroll
                for (int i = DS_SPLIT; i < 64; i += 2) swap32_pair(gp[i], gp[i + 1]);
            }
            if (Kx & 16) {
                #pragma unroll
                for (int i = DS_SPLIT; i < 64; i += 2) swap16_pair(gp[i], gp[i + 1]);
            }
            {
                const int low4 = Kx & 15;
                const bool m_f = (low4 & 8) != 0;
                const int n4 = m_f ? (low4 ^ 15) : low4;
                const bool h_f = (n4 & 4) != 0;
                const int q = h_f ? (n4 ^ 7) : n4;   // 0..3
                if (m_f) {
                    #pragma unroll
                    for (int i = DS_SPLIT; i < 64; ++i) gp[i] = dppf<0x140>(gp[i]);
                }
                if (h_f) {
                    #pragma unroll
                    for (int i = DS_SPLIT; i < 64; ++i) gp[i] = dppf<0x141>(gp[i]);
                }
                if (q == 1) {
                    #pragma unroll
                    for (int i = DS_SPLIT; i < 64; ++i) gp[i] = dppf<0xB1>(gp[i]);
                } else if (q == 2) {
                    #pragma unroll
                    for (int i = DS_SPLIT; i < 64; ++i) gp[i] = dppf<0x4E>(gp[i]);
                } else if (q == 3) {
                    #pragma unroll
                    for (int i = DS_SPLIT; i < 64; ++i) gp[i] = dppf<0x1B>(gp[i]);
                }
            }

            // dot via 4 split chains
            float d0 = 0.f, d1 = 0.f, d2 = 0.f, d3 = 0.f;
            #pragma unroll
            for (int i = 0; i < 64; i += 4) {
                d0 = fmaf(g[i + 0], gp[i + 0], d0);
                d1 = fmaf(g[i + 1], gp[i + 1], d1);
                d2 = fmaf(g[i + 2], gp[i + 2], d2);
                d3 = fmaf(g[i + 3], gp[i + 3], d3);
            }
            const float dot = (d0 + d1) + (d2 + d3);

            // rotation params for ordered pair (p,q) = (min,max)
            const bool isp = lane < partner;
            const float dpp = isp ? nself : dpart;
            const float dqq = isp ? dpart : nself;
            float c = 1.f, s = 0.f, tt = 0.f;
            if (dot * dot > 1e-16f * dpp * dqq) {
                float theta = (dqq - dpp) / (2.f * dot);
                tt = 1.f / (fabsf(theta) + sqrtf(1.f + theta * theta));
                if (theta < 0.f) tt = -tt;
                c = rsqrtf(1.f + tt * tt);
                s = tt * c;
            }
            const float sgn = isp ? -s : s;
            #pragma unroll
            for (int i = 0; i < 64; ++i)
                g[i] = fmaf(c, g[i], sgn * gp[i]);
            nself = fmaf(isp ? -tt : tt, dot, nself);
        }
    }

    // epilogue: sigma, f = log(sigma+eps), w = f/sigma^2
    float d;
    {
        float n0 = 0.f, n1 = 0.f, n2 = 0.f, n3 = 0.f;
        #pragma unroll
        for (int i = 0; i < 64; i += 4) {
            n0 = fmaf(g[i + 0], g[i + 0], n0);
            n1 = fmaf(g[i + 1], g[i + 1], n1);
            n2 = fmaf(g[i + 2], g[i + 2], n2);
            n3 = fmaf(g[i + 3], g[i + 3], n3);
        }
        d = (n0 + n1) + (n2 + n3);
    }
    float sigma = sqrtf(d);
    float f = logf(sigma + EPSV);
    float w = f / d;

    // write G back (lane's column scattered across rows -> coalesced stores)
    #pragma unroll
    for (int i = 0; i < 64; ++i) base[i * DOUT + lane] = g[i];
    wbuf[(size_t)mat * 64 + lane] = w;

    if (nrm != nullptr) {
        float nf = f * f;
        #pragma unroll
        for (int off = 32; off >= 1; off >>= 1) nf += __shfl_xor(nf, off, 64);
        if (lane == 0) *nrm = nf;
    }
}

// ---------------- reconstruction: logA = G diag(w) G^T, in place ----------
__global__ __launch_bounds__(256) void recon_log_kernel(
    float* __restrict__ Q, float* __restrict__ K, float* __restrict__ V,
    const float* __restrict__ wbuf)
{
    __shared__ float Gs[64][LSTR];
    __shared__ float Bs[64][LSTR];
    __shared__ float ws[64];
    const int t = threadIdx.x;
    const int mat = blockIdx.x;
    float* base;
    if (mat < NMAT)          base = Q + (size_t)mat * DD;
    else if (mat < 2 * NMAT) base = K + (size_t)(mat - NMAT) * DD;
    else                     base = V + (size_t)(mat - 2 * NMAT) * DD;

    for (int idx = t; idx < DD; idx += 256)
        Gs[idx >> 6][idx & 63] = base[idx];
    if (t < 64) ws[t] = wbuf[(size_t)mat * 64 + t];
    __syncthreads();
    for (int idx = t; idx < DD; idx += 256) {
        int r = idx >> 6, c = idx & 63;
        Bs[r][c] = Gs[r][c] * ws[c];
    }
    __syncthreads();
    // out[i][j] = sum_k Bs[i][k] * Gs[j][k] ; 4x4 register tile per thread
    const int ti = t >> 4, tj = t & 15;
    float acc[4][4];
    #pragma unroll
    for (int i = 0; i < 4; ++i)
        #pragma unroll
        for (int j = 0; j < 4; ++j) acc[i][j] = 0.f;
    for (int k4 = 0; k4 < 64; k4 += 4) {
        float4 a[4], b[4];
        #pragma unroll
        for (int d = 0; d < 4; ++d) a[d] = *(const float4*)&Bs[4 * ti + d][k4];
        #pragma unroll
        for (int d = 0; d < 4; ++d) b[d] = *(const float4*)&Gs[4 * tj + d][k4];
        #pragma unroll
        for (int kk = 0; kk < 4; ++kk) {
            #pragma unroll
            for (int i = 0; i < 4; ++i) {
                float av = ((const float*)&a[i])[kk];
                #pragma unroll
                for (int j = 0; j < 4; ++j)
                    acc[i][j] += av * ((const float*)&b[j])[kk];
            }
        }
    }
    #pragma unroll
    for (int i = 0; i < 4; ++i) {
        float4 v;
        v.x = acc[i][0]; v.y = acc[i][1]; v.z = acc[i][2]; v.w = acc[i][3];
        *(float4*)(base + (4 * ti + i) * DOUT + 4 * tj) = v;
    }
}

// ---------------- scores + softmax (per batch) ----------------------------
__global__ __launch_bounds__(256) void scores_kernel(
    const float* __restrict__ logK, const float* __restrict__ logQ,
    const float* __restrict__ kn, const float* __restrict__ qn,
    float* __restrict__ prob)
{
    __shared__ float kf_t[64][65];
    __shared__ float qf_t[64][65];
    __shared__ float sc[64][65];
    __shared__ float mx[64], sm[64];
    const int b = blockIdx.x;
    const int t = threadIdx.x;
    const int ti = t >> 4, tjj = t & 15;
    float acc[4][4];
    #pragma unroll
    for (int di = 0; di < 4; ++di)
        #pragma unroll
        for (int dj = 0; dj < 4; ++dj) acc[di][dj] = 0.f;

    const float* Kb = logK + (size_t)b * M * DD;
    const float* Qb = logQ + (size_t)b * M * DD;
    for (int cf = 0; cf < DD; cf += 64) {
        __syncthreads();
        for (int idx = t; idx < 64 * 64; idx += 256) {
            int r = idx >> 6, c = idx & 63;
            kf_t[r][c] = Kb[(size_t)r * DD + cf + c];
            qf_t[r][c] = Qb[(size_t)r * DD + cf + c];
        }
        __syncthreads();
        for (int f = 0; f < 64; ++f) {
            float kv[4], qv[4];
            #pragma unroll
            for (int d = 0; d < 4; ++d) { kv[d] = kf_t[4 * ti + d][f]; qv[d] = qf_t[4 * tjj + d][f]; }
            #pragma unroll
            for (int di = 0; di < 4; ++di)
                #pragma unroll
                for (int dj = 0; dj < 4; ++dj)
                    acc[di][dj] += kv[di] * qv[dj];
        }
    }
    __syncthreads();
    #pragma unroll
    for (int di = 0; di < 4; ++di) {
        #pragma unroll
        for (int dj = 0; dj < 4; ++dj) {
            int i = 4 * ti + di, j = 4 * tjj + dj;
            float dist = kn[b * 64 + i] + qn[b * 64 + j] - 2.f * acc[di][dj];
            dist = fmaxf(dist, 0.f) + 64.f * EPSV;
            sc[i][j] = 1.f / (1.f + log1pf(dist));
        }
    }
    __syncthreads();
    if (t < 64) {
        int j = t;
        float m = -1e30f;
        for (int i = 0; i < 64; ++i) m = fmaxf(m, sc[i][j]);
        float ssum = 0.f;
        for (int i = 0; i < 64; ++i) ssum += expf(sc[i][j] - m);
        mx[j] = m; sm[j] = ssum;
    }
    __syncthreads();
    float* Pb = prob + (size_t)b * M * M;
    for (int idx = t; idx < 64 * 64; idx += 256) {
        int j = idx >> 6, i = idx & 63;
        Pb[idx] = expf(sc[i][j] - mx[j]) / sm[j];
    }
}

// ---------------- mixed = prob @ vf  (one block per output row) -----------
__global__ __launch_bounds__(256) void mixed_kernel(
    const float* __restrict__ prob, const float* __restrict__ logV,
    float* __restrict__ mixed)
{
    __shared__ float pr[64];
    const int n = blockIdx.x;        // b*64 + j
    const int b = n >> 6, j = n & 63;
    const int t = threadIdx.x;
    if (t < 64) pr[t] = prob[((size_t)b * 64 + j) * 64 + t];
    __syncthreads();
    const float4* Vb = (const float4*)(logV + (size_t)b * M * DD);
    float4 acc[4];
    #pragma unroll
    for (int u = 0; u < 4; ++u) acc[u] = make_float4(0.f, 0.f, 0.f, 0.f);
    for (int i = 0; i < 64; ++i) {
        float p = pr[i];
        const float4* row = Vb + (size_t)i * (DD / 4);
        #pragma unroll
        for (int u = 0; u < 4; ++u) {
            float4 v = row[t + 256 * u];
            acc[u].x += p * v.x; acc[u].y += p * v.y;
            acc[u].z += p * v.z; acc[u].w += p * v.w;
        }
    }
    float4* Mp = (float4*)(mixed + (size_t)n * DD);
    #pragma unroll
    for (int u = 0; u < 4; ++u) Mp[t + 256 * u] = acc[u];
}

// ---------------- exp via scaling-and-squaring Taylor (deg 8) -------------
__device__ __forceinline__ void mm64(const float (*A)[LSTR], const float (*B)[LSTR],
                                     float (*C)[LSTR], int t)
{
    const int ti = t >> 4, tj = t & 15;
    float acc[4][4];
    #pragma unroll
    for (int i = 0; i < 4; ++i)
        #pragma unroll
        for (int j = 0; j < 4; ++j) acc[i][j] = 0.f;
    for (int k4 = 0; k4 < 64; k4 += 4) {
        float4 a[4];
        #pragma unroll
        for (int d = 0; d < 4; ++d) a[d] = *(const float4*)&A[4 * ti + d][k4];
        #pragma unroll
        for (int kk = 0; kk < 4; ++kk) {
            float4 bv = *(const float4*)&B[k4 + kk][4 * tj];
            #pragma unroll
            for (int i = 0; i < 4; ++i) {
                float av = ((const float*)&a[i])[kk];
                acc[i][0] += av * bv.x;
                acc[i][1] += av * bv.y;
                acc[i][2] += av * bv.z;
                acc[i][3] += av * bv.w;
            }
        }
    }
    #pragma unroll
    for (int i = 0; i < 4; ++i)
        #pragma unroll
        for (int j = 0; j < 4; ++j)
            C[4 * ti + i][4 * tj + j] = acc[i][j];
}

__global__ __launch_bounds__(256) void exp_ss_kernel(
    const float* __restrict__ in, float* __restrict__ out)
{
    __shared__ float Bs[64][LSTR];
    __shared__ float Ps[64][LSTR];
    __shared__ float Ts[64][LSTR];
    __shared__ float red[64];
    __shared__ int s_sh;
    __shared__ float scl_sh;
    const int t = threadIdx.x;
    const float* Ap = in + (size_t)blockIdx.x * DD;
    float* Gp = out + (size_t)blockIdx.x * DD;

    for (int idx = t; idx < DD; idx += 256) {
        Bs[idx >> 6][idx & 63] = Ap[idx];
    }
    __syncthreads();
    if (t < 64) {
        float s = 0.f;
        for (int c = 0; c < 64; ++c) s += fabsf(Bs[t][c]);
        red[t] = s;
    }
    __syncthreads();
    if (t == 0) {
        float mx = 0.f;
        for (int k = 0; k < 64; ++k) mx = fmaxf(mx, red[k]);
        int s = 0;
        while (mx > 0.7f && s < 30) { mx *= 0.5f; ++s; }
        s_sh = s;
        scl_sh = ldexpf(1.f, -s);
    }
    __syncthreads();
    const int nsq = s_sh;
    const float scl = scl_sh;
    // scale B in place; init P = I + B/8  (degree-8 Taylor, ||B||1 <= 0.7)
    for (int idx = t; idx < DD; idx += 256) {
        int r = idx >> 6, c = idx & 63;
        float b = Bs[r][c] * scl;
        Bs[r][c] = b;
        Ps[r][c] = b * 0.125f + ((r == c) ? 1.f : 0.f);
    }
    __syncthreads();
    // Horner: P <- I + (B*P)/k for k = 7..1
    #pragma unroll 1
    for (int k = 7; k >= 1; --k) {
        mm64(Bs, Ps, Ts, t);
        __syncthreads();
        float rk = 1.f / (float)k;
        for (int idx = t; idx < DD; idx += 256) {
            int r = idx >> 6, c = idx & 63;
            Ps[r][c] = Ts[r][c] * rk + ((r == c) ? 1.f : 0.f);
        }
        __syncthreads();
    }
    // squarings
    #pragma unroll 1
    for (int j = 0; j < nsq; ++j) {
        mm64(Ps, Ps, Ts, t);
        __syncthreads();
        for (int idx = t; idx < DD; idx += 256)
            Ps[idx >> 6][idx & 63] = Ts[idx >> 6][idx & 63];
        __syncthreads();
    }
    for (int idx = t; idx < DD; idx += 256)
        Gp[idx] = Ps[idx >> 6][idx & 63];
}

extern "C" void kernel_launch(void* const* d_in, const int* in_sizes, int n_in,
                              void* d_out, int out_size, void* d_ws, size_t ws_size,
                              hipStream_t stream) {
    const float* x  = (const float*)d_in[0];
    const float* Wq = (const float*)d_in[1];
    const float* Wk = (const float*)d_in[2];
    const float* Wv = (const float*)d_in[3];
    float* out = (float*)d_out;
    float* ws  = (float*)d_ws;

    // ws layout (floats): Q | K | qn | kn | prob | wbuf ; V/logV in d_out.
    float* Q    = ws;
    float* K    = Q + (size_t)NMAT * DD;
    float* qn   = K + (size_t)NMAT * DD;
    float* kn   = qn + NMAT;
    float* prob = kn + NMAT;
    float* wbuf = prob + (size_t)BS * M * M;
    float* V    = out;        // logV staged in d_out
    float* mixed = Q;         // overwrites logQ after scores

    transform_kernel<<<NMAT, 256, 0, stream>>>(x, Wq, Wk, Wv, Q, K, V);
    jacobi1s_kernel<<<(3 * NMAT) / 4, 256, 0, stream>>>(Q, K, V, wbuf, qn, kn);
    recon_log_kernel<<<3 * NMAT, 256, 0, stream>>>(Q, K, V, wbuf);
    scores_kernel<<<BS, 256, 0, stream>>>(K, Q, kn, qn, prob);
    mixed_kernel<<<NMAT, 256, 0, stream>>>(prob, V, mixed);
    exp_ss_kernel<<<NMAT, 256, 0, stream>>>(mixed, out);
}

// Round 16
// 2250.060 us; speedup vs baseline: 1.2614x; 1.0215x over previous
//
#include <hip/hip_runtime.h>
#include <math.h>

#define BS 32
#define M 64
#define NMAT 2048      // BS*M
#define DIN 100
#define DOUT 64
#define DD 4096        // DOUT*DOUT
#define EPSV 1e-6f
#define NSWEEP_1S 6
#define DS_SPLIT 44    // R13 optimum: [0,44) ds_bpermute, [44,64) VALU
#define LSTR 68        // LDS row stride for matmul tiles: 16B-aligned, <=2-way bank alias
#define WSTR 68        // Ws stride in transform (16B-aligned float4 rows)
#define MTILE 4        // mixed: output rows per block

typedef unsigned int uint2v __attribute__((ext_vector_type(2)));

__device__ __forceinline__ float bperm(int addr, float v) {
    return __int_as_float(__builtin_amdgcn_ds_bpermute(addr, __float_as_int(v)));
}

// DPP lane permute (VALU pipe): 0xB1=lane^1, 0x4E=lane^2, 0x1B=lane^3,
// 0x141=lane^7 (row_half_mirror), 0x140=lane^15 (row_mirror).
template <int CTRL>
__device__ __forceinline__ float dppf(float x) {
    return __int_as_float(__builtin_amdgcn_mov_dpp(__float_as_int(x), CTRL, 0xF, 0xF, true));
}

// Full lane^32 of TWO independent values in 2 instructions (no cndmask):
// swap(a,b): a'=[a_lo,b_lo], b'=[a_hi,b_hi]  (validated R8/R9)
__device__ __forceinline__ void swap32_pair(float& x, float& y) {
#if __has_builtin(__builtin_amdgcn_permlane32_swap)
    uint2v r1 = __builtin_amdgcn_permlane32_swap(__float_as_uint(x), __float_as_uint(y), false, false);
    uint2v r2 = __builtin_amdgcn_permlane32_swap(r1[1], r1[0], false, false);
    x = __uint_as_float(r2[0]);
    y = __uint_as_float(r2[1]);
#else
    int a = ((threadIdx.x & 63) ^ 32) << 2;
    x = bperm(a, x); y = bperm(a, y);
#endif
}
__device__ __forceinline__ void swap16_pair(float& x, float& y) {
#if __has_builtin(__builtin_amdgcn_permlane16_swap)
    uint2v r1 = __builtin_amdgcn_permlane16_swap(__float_as_uint(x), __float_as_uint(y), false, false);
    uint2v r2 = __builtin_amdgcn_permlane16_swap(r1[1], r1[0], false, false);
    x = __uint_as_float(r2[0]);
    y = __uint_as_float(r2[1]);
#else
    int a = ((threadIdx.x & 63) ^ 16) << 2;
    x = bperm(a, x); y = bperm(a, y);
#endif
}

// ---------------- transform: S = W^T X W for each of q,k,v ----------------
// X read directly from global (broadcast float4 along k, L1-cached);
// Ws float4-vectorized (stride 68). Bit-identical to R15.
__global__ __launch_bounds__(256) void transform_kernel(
    const float* __restrict__ x,
    const float* __restrict__ Wq, const float* __restrict__ Wk, const float* __restrict__ Wv,
    float* __restrict__ Qo, float* __restrict__ Ko, float* __restrict__ Vo)
{
    __shared__ float Ws[DIN][WSTR];     // 100x68 = 27.2KB
    __shared__ float Ts[DIN][DOUT + 1]; // 100x65 = 26KB
    const int n = blockIdx.x;
    const int t = threadIdx.x;
    const float* Xp = x + (size_t)n * DIN * DIN;

    const float* Wlist[3] = {Wq, Wk, Wv};
    float* Olist[3] = {Qo, Ko, Vo};
    const int tj = t & 63;   // 0..63
    const int tp = t >> 6;   // 0..3

    for (int w = 0; w < 3; ++w) {
        __syncthreads();     // Ws/Ts free
        const float* W = Wlist[w];
        for (int idx = t; idx < DIN * DOUT; idx += 256)
            Ws[idx / DOUT][idx % DOUT] = W[idx];
        __syncthreads();
        // T = X * W : thread computes T[p][tj] for p = tp + 4*pi.
        float acc[25];
        #pragma unroll
        for (int i = 0; i < 25; ++i) acc[i] = 0.f;
        for (int qq = 0; qq < DIN; qq += 4) {
            float4 xv[25];
            #pragma unroll
            for (int pi = 0; pi < 25; ++pi)
                xv[pi] = *(const float4*)&Xp[(size_t)(tp + 4 * pi) * DIN + qq];
            #pragma unroll
            for (int kk = 0; kk < 4; ++kk) {
                float wv = Ws[qq + kk][tj];
                #pragma unroll
                for (int pi = 0; pi < 25; ++pi)
                    acc[pi] = fmaf(((const float*)&xv[pi])[kk], wv, acc[pi]);
            }
        }
        #pragma unroll
        for (int pi = 0; pi < 25; ++pi)
            Ts[tp + 4 * pi][tj] = acc[pi];
        __syncthreads();
        // S = W^T * T : thread computes S[i][tj] for i = 16*tp + ii
        float sacc[16];
        #pragma unroll
        for (int i = 0; i < 16; ++i) sacc[i] = 0.f;
        for (int p = 0; p < DIN; ++p) {
            float tv = Ts[p][tj];
            #pragma unroll
            for (int v = 0; v < 4; ++v) {
                float4 wv = *(const float4*)&Ws[p][16 * tp + 4 * v];
                sacc[4 * v + 0] = fmaf(wv.x, tv, sacc[4 * v + 0]);
                sacc[4 * v + 1] = fmaf(wv.y, tv, sacc[4 * v + 1]);
                sacc[4 * v + 2] = fmaf(wv.z, tv, sacc[4 * v + 2]);
                sacc[4 * v + 3] = fmaf(wv.w, tv, sacc[4 * v + 3]);
            }
        }
        float* Op = Olist[w] + (size_t)n * DD;
        #pragma unroll
        for (int ii = 0; ii < 16; ++ii)
            Op[(16 * tp + ii) * DOUT + tj] = sacc[ii];
    }
}

// ---------------- one-sided Jacobi (SVD) — one wave per matrix ------------
// R13 optimum (1527us): two-pipe exchange, [0,44) DS bpermute, [44,64) VALU
// (DPP + permlane pair-swaps), __launch_bounds__(256,3), 6 sweeps.
__global__ __launch_bounds__(256, 3) void jacobi1s_kernel(
    float* __restrict__ Q, float* __restrict__ K, float* __restrict__ V,
    float* __restrict__ wbuf, float* __restrict__ qn, float* __restrict__ kn)
{
    const int lane = threadIdx.x & 63;
    const int wid  = threadIdx.x >> 6;
    const int mat  = blockIdx.x * 4 + wid;
    float* base;
    float* nrm = nullptr;
    if (mat < NMAT)          { base = Q + (size_t)mat * DD;            nrm = qn + mat; }
    else if (mat < 2 * NMAT) { base = K + (size_t)(mat - NMAT) * DD;   nrm = kn + (mat - NMAT); }
    else                     { base = V + (size_t)(mat - 2 * NMAT) * DD; }

    // Lane `lane` owns column `lane`. A is symmetric -> column == row.
    float g[64];
    {
        const float4* rp = (const float4*)(base + (size_t)lane * DOUT);
        #pragma unroll
        for (int i = 0; i < 16; ++i) {
            float4 v = rp[i];
            g[4 * i + 0] = v.x; g[4 * i + 1] = v.y;
            g[4 * i + 2] = v.z; g[4 * i + 3] = v.w;
        }
    }

    for (int sw = 0; sw < NSWEEP_1S; ++sw) {
        // exact norm at sweep start (kills incremental drift)
        float nself;
        {
            float n0 = 0.f, n1 = 0.f, n2 = 0.f, n3 = 0.f;
            #pragma unroll
            for (int i = 0; i < 64; i += 4) {
                n0 = fmaf(g[i + 0], g[i + 0], n0);
                n1 = fmaf(g[i + 1], g[i + 1], n1);
                n2 = fmaf(g[i + 2], g[i + 2], n2);
                n3 = fmaf(g[i + 3], g[i + 3], n3);
            }
            nself = (n0 + n1) + (n2 + n3);
        }
        #pragma unroll 1
        for (int rr = 0; rr < 63; ++rr) {
            const int Kx = rr + 1;
            const int partner = lane ^ Kx;
            const int paddr = partner << 2;
            const float dpart = bperm(paddr, nself);

            float gp[64];
            // ---- DS portion: elements [0,DS_SPLIT) via bpermute ----
            #pragma unroll
            for (int i = 0; i < DS_SPLIT; ++i) gp[i] = bperm(paddr, g[i]);
            // ---- VALU portion: elements [DS_SPLIT,64) via DPP/permlane ----
            #pragma unroll
            for (int i = DS_SPLIT; i < 64; ++i) gp[i] = g[i];
            if (Kx & 32) {
                #pragma unroll
                for (int i = DS_SPLIT; i < 64; i += 2) swap32_pair(gp[i], gp[i + 1]);
            }
            if (Kx & 16) {
                #pragma unroll
                for (int i = DS_SPLIT; i < 64; i += 2) swap16_pair(gp[i], gp[i + 1]);
            }
            {
                const int low4 = Kx & 15;
                const bool m_f = (low4 & 8) != 0;
                const int n4 = m_f ? (low4 ^ 15) : low4;
                const bool h_f = (n4 & 4) != 0;
                const int q = h_f ? (n4 ^ 7) : n4;   // 0..3
                if (m_f) {
                    #pragma unroll
                    for (int i = DS_SPLIT; i < 64; ++i) gp[i] = dppf<0x140>(gp[i]);
                }
                if (h_f) {
                    #pragma unroll
                    for (int i = DS_SPLIT; i < 64; ++i) gp[i] = dppf<0x141>(gp[i]);
                }
                if (q == 1) {
                    #pragma unroll
                    for (int i = DS_SPLIT; i < 64; ++i) gp[i] = dppf<0xB1>(gp[i]);
                } else if (q == 2) {
                    #pragma unroll
                    for (int i = DS_SPLIT; i < 64; ++i) gp[i] = dppf<0x4E>(gp[i]);
                } else if (q == 3) {
                    #pragma unroll
                    for (int i = DS_SPLIT; i < 64; ++i) gp[i] = dppf<0x1B>(gp[i]);
                }
            }

            // dot via 4 split chains
            float d0 = 0.f, d1 = 0.f, d2 = 0.f, d3 = 0.f;
            #pragma unroll
            for (int i = 0; i < 64; i += 4) {
                d0 = fmaf(g[i + 0], gp[i + 0], d0);
                d1 = fmaf(g[i + 1], gp[i + 1], d1);
                d2 = fmaf(g[i + 2], gp[i + 2], d2);
                d3 = fmaf(g[i + 3], gp[i + 3], d3);
            }
            const float dot = (d0 + d1) + (d2 + d3);

            // rotation params for ordered pair (p,q) = (min,max)
            const bool isp = lane < partner;
            const float dpp = isp ? nself : dpart;
            const float dqq = isp ? dpart : nself;
            float c = 1.f, s = 0.f, tt = 0.f;
            if (dot * dot > 1e-16f * dpp * dqq) {
                float theta = (dqq - dpp) / (2.f * dot);
                tt = 1.f / (fabsf(theta) + sqrtf(1.f + theta * theta));
                if (theta < 0.f) tt = -tt;
                c = rsqrtf(1.f + tt * tt);
                s = tt * c;
            }
            const float sgn = isp ? -s : s;
            #pragma unroll
            for (int i = 0; i < 64; ++i)
                g[i] = fmaf(c, g[i], sgn * gp[i]);
            nself = fmaf(isp ? -tt : tt, dot, nself);
        }
    }

    // epilogue: sigma, f = log(sigma+eps), w = f/sigma^2
    float d;
    {
        float n0 = 0.f, n1 = 0.f, n2 = 0.f, n3 = 0.f;
        #pragma unroll
        for (int i = 0; i < 64; i += 4) {
            n0 = fmaf(g[i + 0], g[i + 0], n0);
            n1 = fmaf(g[i + 1], g[i + 1], n1);
            n2 = fmaf(g[i + 2], g[i + 2], n2);
            n3 = fmaf(g[i + 3], g[i + 3], n3);
        }
        d = (n0 + n1) + (n2 + n3);
    }
    float sigma = sqrtf(d);
    float f = logf(sigma + EPSV);
    float w = f / d;

    // write G back (lane's column scattered across rows -> coalesced stores)
    #pragma unroll
    for (int i = 0; i < 64; ++i) base[i * DOUT + lane] = g[i];
    wbuf[(size_t)mat * 64 + lane] = w;

    if (nrm != nullptr) {
        float nf = f * f;
        #pragma unroll
        for (int off = 32; off >= 1; off >>= 1) nf += __shfl_xor(nf, off, 64);
        if (lane == 0) *nrm = nf;
    }
}

// ---------------- reconstruction: logA = G diag(w) G^T, in place ----------
__global__ __launch_bounds__(256) void recon_log_kernel(
    float* __restrict__ Q, float* __restrict__ K, float* __restrict__ V,
    const float* __restrict__ wbuf)
{
    __shared__ float Gs[64][LSTR];
    __shared__ float Bs[64][LSTR];
    __shared__ float ws[64];
    const int t = threadIdx.x;
    const int mat = blockIdx.x;
    float* base;
    if (mat < NMAT)          base = Q + (size_t)mat * DD;
    else if (mat < 2 * NMAT) base = K + (size_t)(mat - NMAT) * DD;
    else                     base = V + (size_t)(mat - 2 * NMAT) * DD;

    for (int idx = t; idx < DD; idx += 256)
        Gs[idx >> 6][idx & 63] = base[idx];
    if (t < 64) ws[t] = wbuf[(size_t)mat * 64 + t];
    __syncthreads();
    for (int idx = t; idx < DD; idx += 256) {
        int r = idx >> 6, c = idx & 63;
        Bs[r][c] = Gs[r][c] * ws[c];
    }
    __syncthreads();
    // out[i][j] = sum_k Bs[i][k] * Gs[j][k] ; 4x4 register tile per thread
    const int ti = t >> 4, tj = t & 15;
    float acc[4][4];
    #pragma unroll
    for (int i = 0; i < 4; ++i)
        #pragma unroll
        for (int j = 0; j < 4; ++j) acc[i][j] = 0.f;
    for (int k4 = 0; k4 < 64; k4 += 4) {
        float4 a[4], b[4];
        #pragma unroll
        for (int d = 0; d < 4; ++d) a[d] = *(const float4*)&Bs[4 * ti + d][k4];
        #pragma unroll
        for (int d = 0; d < 4; ++d) b[d] = *(const float4*)&Gs[4 * tj + d][k4];
        #pragma unroll
        for (int kk = 0; kk < 4; ++kk) {
            #pragma unroll
            for (int i = 0; i < 4; ++i) {
                float av = ((const float*)&a[i])[kk];
                #pragma unroll
                for (int j = 0; j < 4; ++j)
                    acc[i][j] += av * ((const float*)&b[j])[kk];
            }
        }
    }
    #pragma unroll
    for (int i = 0; i < 4; ++i) {
        float4 v;
        v.x = acc[i][0]; v.y = acc[i][1]; v.z = acc[i][2]; v.w = acc[i][3];
        *(float4*)(base + (4 * ti + i) * DOUT + 4 * tj) = v;
    }
}

// ---------------- scores + softmax (per batch) ----------------------------
__global__ __launch_bounds__(256) void scores_kernel(
    const float* __restrict__ logK, const float* __restrict__ logQ,
    const float* __restrict__ kn, const float* __restrict__ qn,
    float* __restrict__ prob)
{
    __shared__ float kf_t[64][65];
    __shared__ float qf_t[64][65];
    __shared__ float sc[64][65];
    __shared__ float mx[64], sm[64];
    const int b = blockIdx.x;
    const int t = threadIdx.x;
    const int ti = t >> 4, tjj = t & 15;
    float acc[4][4];
    #pragma unroll
    for (int di = 0; di < 4; ++di)
        #pragma unroll
        for (int dj = 0; dj < 4; ++dj) acc[di][dj] = 0.f;

    const float* Kb = logK + (size_t)b * M * DD;
    const float* Qb = logQ + (size_t)b * M * DD;
    for (int cf = 0; cf < DD; cf += 64) {
        __syncthreads();
        for (int idx = t; idx < 64 * 64; idx += 256) {
            int r = idx >> 6, c = idx & 63;
            kf_t[r][c] = Kb[(size_t)r * DD + cf + c];
            qf_t[r][c] = Qb[(size_t)r * DD + cf + c];
        }
        __syncthreads();
        for (int f = 0; f < 64; ++f) {
            float kv[4], qv[4];
            #pragma unroll
            for (int d = 0; d < 4; ++d) { kv[d] = kf_t[4 * ti + d][f]; qv[d] = qf_t[4 * tjj + d][f]; }
            #pragma unroll
            for (int di = 0; di < 4; ++di)
                #pragma unroll
                for (int dj = 0; dj < 4; ++dj)
                    acc[di][dj] += kv[di] * qv[dj];
        }
    }
    __syncthreads();
    #pragma unroll
    for (int di = 0; di < 4; ++di) {
        #pragma unroll
        for (int dj = 0; dj < 4; ++dj) {
            int i = 4 * ti + di, j = 4 * tjj + dj;
            float dist = kn[b * 64 + i] + qn[b * 64 + j] - 2.f * acc[di][dj];
            dist = fmaxf(dist, 0.f) + 64.f * EPSV;
            sc[i][j] = 1.f / (1.f + log1pf(dist));
        }
    }
    __syncthreads();
    if (t < 64) {
        int j = t;
        float m = -1e30f;
        for (int i = 0; i < 64; ++i) m = fmaxf(m, sc[i][j]);
        float ssum = 0.f;
        for (int i = 0; i < 64; ++i) ssum += expf(sc[i][j] - m);
        mx[j] = m; sm[j] = ssum;
    }
    __syncthreads();
    float* Pb = prob + (size_t)b * M * M;
    for (int idx = t; idx < 64 * 64; idx += 256) {
        int j = idx >> 6, i = idx & 63;
        Pb[idx] = expf(sc[i][j] - mx[j]) / sm[j];
    }
}

// ---------------- mixed = prob @ vf  (MTILE output rows per block) --------
// R16: 4 rows/block -> logV batch read once per block (2.1GB -> 0.54GB).
// Per-row accumulation order (i ascending, x/y/z/w) identical to R15 ->
// bit-identical output.
__global__ __launch_bounds__(256) void mixed_kernel(
    const float* __restrict__ prob, const float* __restrict__ logV,
    float* __restrict__ mixed)
{
    __shared__ float pr[MTILE][64];
    const int blk = blockIdx.x;          // b*16 + tile
    const int b = blk >> 4, tile = blk & 15;
    const int t = threadIdx.x;
    for (int idx = t; idx < MTILE * 64; idx += 256) {
        int r = idx >> 6, i = idx & 63;
        pr[r][i] = prob[((size_t)b * 64 + tile * MTILE + r) * 64 + i];
    }
    __syncthreads();
    const float4* Vb = (const float4*)(logV + (size_t)b * M * DD);
    float4 acc[MTILE][4];
    #pragma unroll
    for (int r = 0; r < MTILE; ++r)
        #pragma unroll
        for (int u = 0; u < 4; ++u) acc[r][u] = make_float4(0.f, 0.f, 0.f, 0.f);
    for (int i = 0; i < 64; ++i) {
        float4 v[4];
        #pragma unroll
        for (int u = 0; u < 4; ++u) v[u] = Vb[(size_t)i * (DD / 4) + t + 256 * u];
        #pragma unroll
        for (int r = 0; r < MTILE; ++r) {
            float p = pr[r][i];
            #pragma unroll
            for (int u = 0; u < 4; ++u) {
                acc[r][u].x += p * v[u].x; acc[r][u].y += p * v[u].y;
                acc[r][u].z += p * v[u].z; acc[r][u].w += p * v[u].w;
            }
        }
    }
    #pragma unroll
    for (int r = 0; r < MTILE; ++r) {
        float4* Mp = (float4*)(mixed + (size_t)(b * 64 + tile * MTILE + r) * DD);
        #pragma unroll
        for (int u = 0; u < 4; ++u) Mp[t + 256 * u] = acc[r][u];
    }
}

// ---------------- exp via scaling-and-squaring Taylor (deg 8) -------------
// R16: fused matmul epilogue (C = acc*rk + addI*I) with P0/P1 ping-pong —
// removes the separate update/copy passes and halves barriers. Value and
// rounding identical to R15 (acc order unchanged; store was exact).
__device__ __forceinline__ void mm64_fused(const float (*A)[LSTR], const float (*B)[LSTR],
                                           float (*C)[LSTR], int t, float rk, bool addI)
{
    const int ti = t >> 4, tj = t & 15;
    float acc[4][4];
    #pragma unroll
    for (int i = 0; i < 4; ++i)
        #pragma unroll
        for (int j = 0; j < 4; ++j) acc[i][j] = 0.f;
    for (int k4 = 0; k4 < 64; k4 += 4) {
        float4 a[4];
        #pragma unroll
        for (int d = 0; d < 4; ++d) a[d] = *(const float4*)&A[4 * ti + d][k4];
        #pragma unroll
        for (int kk = 0; kk < 4; ++kk) {
            float4 bv = *(const float4*)&B[k4 + kk][4 * tj];
            #pragma unroll
            for (int i = 0; i < 4; ++i) {
                float av = ((const float*)&a[i])[kk];
                acc[i][0] += av * bv.x;
                acc[i][1] += av * bv.y;
                acc[i][2] += av * bv.z;
                acc[i][3] += av * bv.w;
            }
        }
    }
    #pragma unroll
    for (int i = 0; i < 4; ++i)
        #pragma unroll
        for (int j = 0; j < 4; ++j) {
            float idv = (addI && (4 * ti + i == 4 * tj + j)) ? 1.f : 0.f;
            C[4 * ti + i][4 * tj + j] = acc[i][j] * rk + idv;
        }
}

__global__ __launch_bounds__(256) void exp_ss_kernel(
    const float* __restrict__ in, float* __restrict__ out)
{
    __shared__ float Bs[64][LSTR];
    __shared__ float P0[64][LSTR];
    __shared__ float P1[64][LSTR];
    __shared__ float red[64];
    __shared__ int s_sh;
    __shared__ float scl_sh;
    const int t = threadIdx.x;
    const float* Ap = in + (size_t)blockIdx.x * DD;
    float* Gp = out + (size_t)blockIdx.x * DD;

    for (int idx = t; idx < DD; idx += 256) {
        Bs[idx >> 6][idx & 63] = Ap[idx];
    }
    __syncthreads();
    if (t < 64) {
        float s = 0.f;
        for (int c = 0; c < 64; ++c) s += fabsf(Bs[t][c]);
        red[t] = s;
    }
    __syncthreads();
    if (t == 0) {
        float mx = 0.f;
        for (int k = 0; k < 64; ++k) mx = fmaxf(mx, red[k]);
        int s = 0;
        while (mx > 0.7f && s < 30) { mx *= 0.5f; ++s; }
        s_sh = s;
        scl_sh = ldexpf(1.f, -s);
    }
    __syncthreads();
    const int nsq = s_sh;
    const float scl = scl_sh;
    // scale B in place; init P0 = I + B/8  (degree-8 Taylor, ||B||1 <= 0.7)
    for (int idx = t; idx < DD; idx += 256) {
        int r = idx >> 6, c = idx & 63;
        float b = Bs[r][c] * scl;
        Bs[r][c] = b;
        P0[r][c] = b * 0.125f + ((r == c) ? 1.f : 0.f);
    }
    __syncthreads();
    float (*Pc)[LSTR] = P0;
    float (*Pn)[LSTR] = P1;
    // Horner: Pn <- I + (Bs*Pc)/k for k = 7..1 (fused epilogue, ping-pong)
    #pragma unroll 1
    for (int k = 7; k >= 1; --k) {
        mm64_fused(Bs, Pc, Pn, t, 1.f / (float)k, true);
        __syncthreads();
        float (*tmp)[LSTR] = Pc; Pc = Pn; Pn = tmp;
    }
    // squarings: Pn <- Pc*Pc, ping-pong
    #pragma unroll 1
    for (int j = 0; j < nsq; ++j) {
        mm64_fused(Pc, Pc, Pn, t, 1.f, false);
        __syncthreads();
        float (*tmp)[LSTR] = Pc; Pc = Pn; Pn = tmp;
    }
    for (int idx = t; idx < DD; idx += 256)
        Gp[idx] = Pc[idx >> 6][idx & 63];
}

extern "C" void kernel_launch(void* const* d_in, const int* in_sizes, int n_in,
                              void* d_out, int out_size, void* d_ws, size_t ws_size,
                              hipStream_t stream) {
    const float* x  = (const float*)d_in[0];
    const float* Wq = (const float*)d_in[1];
    const float* Wk = (const float*)d_in[2];
    const float* Wv = (const float*)d_in[3];
    float* out = (float*)d_out;
    float* ws  = (float*)d_ws;

    // ws layout (floats): Q | K | qn | kn | prob | wbuf ; V/logV in d_out.
    float* Q    = ws;
    float* K    = Q + (size_t)NMAT * DD;
    float* qn   = K + (size_t)NMAT * DD;
    float* kn   = qn + NMAT;
    float* prob = kn + NMAT;
    float* wbuf = prob + (size_t)BS * M * M;
    float* V    = out;        // logV staged in d_out
    float* mixed = Q;         // overwrites logQ after scores

    transform_kernel<<<NMAT, 256, 0, stream>>>(x, Wq, Wk, Wv, Q, K, V);
    jacobi1s_kernel<<<(3 * NMAT) / 4, 256, 0, stream>>>(Q, K, V, wbuf, qn, kn);
    recon_log_kernel<<<3 * NMAT, 256, 0, stream>>>(Q, K, V, wbuf);
    scores_kernel<<<BS, 256, 0, stream>>>(K, Q, kn, qn, prob);
    mixed_kernel<<<BS * (M / MTILE), 256, 0, stream>>>(prob, V, mixed);
    exp_ss_kernel<<<NMAT, 256, 0, stream>>>(mixed, out);
}